// Round 10
// baseline (58.025 us; speedup 1.0000x reference)
//
#include <hip/hip_runtime.h>

// B=256, T=256, D=384, HD=64
typedef __attribute__((ext_vector_type(8))) short bf16x8;
typedef __attribute__((ext_vector_type(4))) float f32x4;

__device__ inline unsigned short f2bf(float f) {
    unsigned u = __float_as_uint(f);
    return (unsigned short)((u + 0x7fffu + ((u >> 16) & 1u)) >> 16);
}
__device__ inline bf16x8 pack8(float4 a, float4 b) {
    bf16x8 t;
    t[0] = (short)f2bf(a.x); t[1] = (short)f2bf(a.y);
    t[2] = (short)f2bf(a.z); t[3] = (short)f2bf(a.w);
    t[4] = (short)f2bf(b.x); t[5] = (short)f2bf(b.y);
    t[6] = (short)f2bf(b.z); t[7] = (short)f2bf(b.w);
    return t;
}
__device__ inline void gload16(const void* g, void* l) {
    __builtin_amdgcn_global_load_lds(
        (const __attribute__((address_space(1))) unsigned*)g,
        (__attribute__((address_space(3))) unsigned*)l, 16, 0, 0);
}

// ---------------------------------------------------------------------------
// Kernel 0 (R7-verified): W = [Wq;Wk;Wv] -> bf16, frag-major + pre-swizzled:
//   Wp[kc*6144 + (((g*192 + col) ^ g) << 3) + kl] = W[col][kc*32 + g*8 + kl]
// ---------------------------------------------------------------------------
__global__ void wconv(const float* __restrict__ Wq, const float* __restrict__ Wk,
                      const float* __restrict__ Wv, short* __restrict__ Wp) {
    int i = blockIdx.x * 256 + threadIdx.x;
    if (i >= 192 * 384) return;
    int col = i / 384;
    int k   = i - col * 384;
    const float* src = col < 64 ? (Wq + col * 384)
                     : col < 128 ? (Wk + (col - 64) * 384)
                                 : (Wv + (col - 128) * 384);
    int kc = k >> 5, g = (k >> 3) & 3, kl = k & 7;
    Wp[kc * 6144 + (((g * 192 + col) ^ g) << 3) + kl] = (short)f2bf(src[k]);
}

// ---------------------------------------------------------------------------
// Kernel 1: QKV projection, x FULLY RESIDENT before the k-loop.
// 1024 blocks x 256 thr (4 waves 2Mx2N, wave = 32 rows x 96 cols, acc 2x6).
// Prologue: TWO contiguous 48 KB bursts of x (rows 0-31, 32-63; 24 float4
//   in flight per thread = 96 KB/block >> BDP -> sequential DRAM at full BW),
//   convert to bf16, write to xs with XOR-swizzled 16B chunks:
//     xs[row*384 + ((chunk ^ (row&7))<<3)], chunk = col/8  (0..47)
//   -> frag reads spread uniformly over banks (8 lanes/bank-quad = min).
// k-loop: x has ZERO VM ops (vmcnt-FIFO trap avoided); only W stages:
//   12 KB/step from pre-packed Wp via global_load_lds, double-buffered,
//   issued before compute, vmcnt(0)+barrier per step (drains W only).
// Epilogue: R8-verbatim repack (overlays wst) + coalesced bf16 stores.
// ---------------------------------------------------------------------------
__global__ __launch_bounds__(256, 2) void qkv_proj(
    const float* __restrict__ x, const short* __restrict__ Wp,
    short* __restrict__ Qw, short* __restrict__ Kw, short* __restrict__ Vw) {
    __shared__ short xs[64 * 384];          // 49152 B, swizzled chunks, no pad
    __shared__ short wst[2 * 6144];         // 24576 B

    const int tid = threadIdx.x;
    const int wv = tid >> 6, lane = tid & 63;
    const int g = lane >> 4, c = lane & 15;
    const int wm = (wv >> 1) * 32, wn = (wv & 1) * 96;
    const size_t m0 = (size_t)blockIdx.x * 64;

#define STAGE_W(S, BUF)                                                       \
    {                                                                         \
        _Pragma("unroll")                                                     \
        for (int i_ = 0; i_ < 3; ++i_) {                                      \
            int seg = wv * 3 + i_;                                            \
            gload16(Wp + (S) * 6144 + seg * 512 + lane * 8,                   \
                    wst + (BUF) * 6144 + seg * 512);                          \
        }                                                                     \
    }

    f32x4 acc[2][6];
#pragma unroll
    for (int i = 0; i < 2; ++i)
#pragma unroll
        for (int j = 0; j < 6; ++j) acc[i][j] = (f32x4){0.f, 0.f, 0.f, 0.f};

    // ---- prologue: deep sequential x bursts + W step 0 ----
    const float4* xA = (const float4*)(x + m0 * 384);   // rows 0-31 flat
    const float4* xB = xA + 3072;                       // rows 32-63 flat
    float4 ta[12], tb[12];
#pragma unroll
    for (int j = 0; j < 6; ++j) {
        int f = 2 * (tid + 256 * j);
        ta[2 * j]     = xA[f];
        ta[2 * j + 1] = xA[f + 1];
    }
#pragma unroll
    for (int j = 0; j < 6; ++j) {
        int f = 2 * (tid + 256 * j);
        tb[2 * j]     = xB[f];
        tb[2 * j + 1] = xB[f + 1];
    }
    STAGE_W(0, 0)
#pragma unroll
    for (int j = 0; j < 6; ++j) {           // convert+write burst A
        int ch = tid + 256 * j;             // 0..1535
        int row = ch / 48, cch = ch - row * 48;
        *(bf16x8*)&xs[row * 384 + ((cch ^ (row & 7)) << 3)] =
            pack8(ta[2 * j], ta[2 * j + 1]);
    }
#pragma unroll
    for (int j = 0; j < 6; ++j) {           // convert+write burst B
        int ch = tid + 256 * j;
        int row = ch / 48, cch = ch - row * 48;
        *(bf16x8*)&xs[(row + 32) * 384 + ((cch ^ (row & 7)) << 3)] =
            pack8(tb[2 * j], tb[2 * j + 1]);
    }
    asm volatile("s_waitcnt vmcnt(0)" ::: "memory");   // W0 (x already drained)
    __syncthreads();

    // ---- k-loop: 12 steps, W-only staging ----
    for (int s = 0; s < 12; ++s) {
        if (s < 11) STAGE_W(s + 1, (s + 1) & 1)
        const short* wb = wst + (s & 1) * 6144;
        bf16x8 af[2], bfr[6];
#pragma unroll
        for (int mi = 0; mi < 2; ++mi) {
            const int row = wm + 16 * mi + c;
            af[mi] = *(const bf16x8*)&xs[row * 384 + (((s * 4 + g) ^ (c & 7)) << 3)];
        }
#pragma unroll
        for (int nj = 0; nj < 6; ++nj)
            bfr[nj] = *(const bf16x8*)&wb[((g * 192 + wn + 16 * nj + c) ^ g) << 3];
#pragma unroll
        for (int mi = 0; mi < 2; ++mi)
#pragma unroll
            for (int nj = 0; nj < 6; ++nj)
                acc[mi][nj] = __builtin_amdgcn_mfma_f32_16x16x32_bf16(
                    af[mi], bfr[nj], acc[mi][nj], 0, 0, 0);
        asm volatile("s_waitcnt vmcnt(0)" ::: "memory");
        __syncthreads();
    }

    // ---- epilogue: acc -> LDS repack (overlays wst) -> coalesced stores.
    // C/D layout (verified): col = c, row = 4g + r within each 16x16 tile.
    short* ep = wst;                        // 64*192 shorts = 24576 B
#pragma unroll
    for (int mi = 0; mi < 2; ++mi)
#pragma unroll
        for (int nj = 0; nj < 6; ++nj) {
            const int row = wm + 16 * mi + 4 * g;
#pragma unroll
            for (int r = 0; r < 4; ++r)
                ep[(row + r) * 192 + wn + 16 * nj + c] = (short)f2bf(acc[mi][nj][r]);
        }
    __syncthreads();
#pragma unroll
    for (int p = 0; p < 2; ++p) {
        int u = tid + 256 * p;              // 0..511: row = u>>3, c8 = u&7
        int row = u >> 3, c8 = u & 7;
        *(uint4*)(Qw + (m0 + row) * 64 + c8 * 8) = *(const uint4*)&ep[row * 192 + c8 * 8];
        *(uint4*)(Kw + (m0 + row) * 64 + c8 * 8) = *(const uint4*)&ep[row * 192 + 64 + c8 * 8];
        *(uint4*)(Vw + (m0 + row) * 64 + c8 * 8) = *(const uint4*)&ep[row * 192 + 128 + c8 * 8];
    }
#undef STAGE_W
}

// ---------------------------------------------------------------------------
// Kernel 2: causal attention (R2/R7-verified, verbatim). 256 blocks x 512 thr,
// LDS 79 KB -> 2 blocks/CU. K [256][72]; V transposed [64][264] XOR-swizzled;
// Q direct global->regs. Wave w: q-tiles 16w and 240-16w (9 kv-tiles each).
// ---------------------------------------------------------------------------
__global__ __launch_bounds__(512, 2) void attn_mfma(
    const short* __restrict__ Qw, const short* __restrict__ Kw,
    const short* __restrict__ Vw, float* __restrict__ out) {
    __shared__ short Ksh[256 * 72];
    __shared__ short Vt[64 * 264];
    __shared__ short Pb[8][640];
    const int tid = threadIdx.x;
    const int wv = tid >> 6, lane = tid & 63;
    const int g = lane >> 4, c = lane & 15;
    const int b = blockIdx.x;
    const short* Qg = Qw + b * 16384;
    const short* Kg = Kw + b * 16384;
    const short* Vg = Vw + b * 16384;

#pragma unroll
    for (int p = 0; p < 4; ++p) {
        int idx = tid + 512 * p;
        int r = idx >> 3, q8 = idx & 7;
        *(uint4*)&Ksh[r * 72 + q8 * 8] = *(const uint4*)(Kg + r * 64 + q8 * 8);
    }
#pragma unroll
    for (int p = 0; p < 4; ++p) {
        int idx = tid + 512 * p;
        int r = idx >> 3, q8 = idx & 7;
        uint4 v = *(const uint4*)(Vg + r * 64 + q8 * 8);
        unsigned vw[4] = {v.x, v.y, v.z, v.w};
        int swz = (q8 & 7) << 3;
#pragma unroll
        for (int w2 = 0; w2 < 4; ++w2) {
            int h0 = q8 * 8 + w2 * 2;
            Vt[((h0 + 0) * 264 + r) ^ swz] = (short)(vw[w2] & 0xffff);
            Vt[((h0 + 1) * 264 + r) ^ swz] = (short)(vw[w2] >> 16);
        }
    }
    __syncthreads();

    for (int half = 0; half < 2; ++half) {
        const int q0 = (half == 0) ? 16 * wv : 240 - 16 * wv;
        bf16x8 qf0 = *(const bf16x8*)(Qg + (q0 + c) * 64 + g * 8);
        bf16x8 qf1 = *(const bf16x8*)(Qg + (q0 + c) * 64 + 32 + g * 8);
        f32x4 o[4];
#pragma unroll
        for (int nj = 0; nj < 4; ++nj) o[nj] = (f32x4){0.f, 0.f, 0.f, 0.f};
        float m[4] = {-INFINITY, -INFINITY, -INFINITY, -INFINITY};
        float ls[4] = {0.f, 0.f, 0.f, 0.f};
        const int jmax = (q0 + 15) >> 5;

        for (int j = 0; j <= jmax; ++j) {
            f32x4 s0 = {0.f, 0.f, 0.f, 0.f}, s1 = {0.f, 0.f, 0.f, 0.f};
            {
                bf16x8 kf;
                kf = *(const bf16x8*)&Ksh[(32 * j + c) * 72 + g * 8];
                s0 = __builtin_amdgcn_mfma_f32_16x16x32_bf16(qf0, kf, s0, 0, 0, 0);
                kf = *(const bf16x8*)&Ksh[(32 * j + c) * 72 + 32 + g * 8];
                s0 = __builtin_amdgcn_mfma_f32_16x16x32_bf16(qf1, kf, s0, 0, 0, 0);
                kf = *(const bf16x8*)&Ksh[(32 * j + 16 + c) * 72 + g * 8];
                s1 = __builtin_amdgcn_mfma_f32_16x16x32_bf16(qf0, kf, s1, 0, 0, 0);
                kf = *(const bf16x8*)&Ksh[(32 * j + 16 + c) * 72 + 32 + g * 8];
                s1 = __builtin_amdgcn_mfma_f32_16x16x32_bf16(qf1, kf, s1, 0, 0, 0);
            }
            float t0[4], t1[4];
#pragma unroll
            for (int r = 0; r < 4; ++r) {
                t0[r] = s0[r] * 0.125f;
                t1[r] = s1[r] * 0.125f;
            }
            if (j == jmax) {   // wave-uniform: diagonal tile, causal mask
                int q = q0 + 4 * g;
#pragma unroll
                for (int r = 0; r < 4; ++r) {
                    if (32 * j + c > q + r) t0[r] = -INFINITY;
                    if (32 * j + 16 + c > q + r) t1[r] = -INFINITY;
                }
            }
            float corr[4], p0[4], p1[4];
#pragma unroll
            for (int r = 0; r < 4; ++r) {
                float v = fmaxf(t0[r], t1[r]);
#pragma unroll
                for (int off = 1; off < 16; off <<= 1) v = fmaxf(v, __shfl_xor(v, off, 16));
                float mn = fmaxf(m[r], v);
                corr[r] = __expf(m[r] - mn);   // first tile: exp(-inf)=0
                m[r] = mn;
                p0[r] = __expf(t0[r] - mn);
                p1[r] = __expf(t1[r] - mn);
                float rs = p0[r] + p1[r];
#pragma unroll
                for (int off = 1; off < 16; off <<= 1) rs += __shfl_xor(rs, off, 16);
                ls[r] = ls[r] * corr[r] + rs;
            }
#pragma unroll
            for (int nj = 0; nj < 4; ++nj) {
                f32x4 t = o[nj];
                t[0] *= corr[0]; t[1] *= corr[1]; t[2] *= corr[2]; t[3] *= corr[3];
                o[nj] = t;
            }
            short* pb = Pb[wv];
#pragma unroll
            for (int r = 0; r < 4; ++r) {
                pb[(4 * g + r) * 40 + c]      = (short)f2bf(p0[r]);
                pb[(4 * g + r) * 40 + 16 + c] = (short)f2bf(p1[r]);
            }
            bf16x8 pfa = *(const bf16x8*)&pb[c * 40 + g * 8];
#pragma unroll
            for (int nj = 0; nj < 4; ++nj) {
                int h = 16 * nj + c;
                int swz = ((2 * nj + (c >> 3)) & 7) << 3;
                bf16x8 vf = *(const bf16x8*)&Vt[(h * 264 + 32 * j + g * 8) ^ swz];
                o[nj] = __builtin_amdgcn_mfma_f32_16x16x32_bf16(pfa, vf, o[nj], 0, 0, 0);
            }
        }
        float inv[4];
#pragma unroll
        for (int r = 0; r < 4; ++r) inv[r] = 1.f / ls[r];
        float* ob = out + ((size_t)b * 256 + q0) * 64;
#pragma unroll
        for (int nj = 0; nj < 4; ++nj)
#pragma unroll
            for (int r = 0; r < 4; ++r)
                ob[(4 * g + r) * 64 + 16 * nj + c] = o[nj][r] * inv[r];
    }
}

// ---------------------------------------------------------------------------
extern "C" void kernel_launch(void* const* d_in, const int* in_sizes, int n_in,
                              void* d_out, int out_size, void* d_ws, size_t ws_size,
                              hipStream_t stream) {
    const float* x  = (const float*)d_in[0];
    const float* Wq = (const float*)d_in[1];
    const float* Wk = (const float*)d_in[2];
    const float* Wv = (const float*)d_in[3];
    float* out = (float*)d_out;

    // ws: Q | K | V (each 65536*64 bf16 = 8 MB) | Wp (73728 shorts)
    short* Qws = (short*)d_ws;
    short* Kws = Qws + (size_t)65536 * 64;
    short* Vws = Kws + (size_t)65536 * 64;
    short* Wp  = Vws + (size_t)65536 * 64;

    wconv<<<dim3(288), dim3(256), 0, stream>>>(Wq, Wk, Wv, Wp);
    qkv_proj<<<dim3(1024), dim3(256), 0, stream>>>(x, Wp, Qws, Kws, Vws);
    attn_mfma<<<dim3(256), dim3(512), 0, stream>>>(Qws, Kws, Vws, out);
}

// Round 11
// 47.072 us; speedup vs baseline: 1.2327x; 1.2327x over previous
//
#include <hip/hip_runtime.h>

// B=256, T=256, D=384, HD=64
typedef __attribute__((ext_vector_type(8))) short bf16x8;
typedef __attribute__((ext_vector_type(4))) float f32x4;

__device__ inline unsigned short f2bf(float f) {
    unsigned u = __float_as_uint(f);
    return (unsigned short)((u + 0x7fffu + ((u >> 16) & 1u)) >> 16);
}
__device__ inline void gload16(const void* g, void* l) {
    __builtin_amdgcn_global_load_lds(
        (const __attribute__((address_space(1))) unsigned*)g,
        (__attribute__((address_space(3))) unsigned*)l, 16, 0, 0);
}

// ---------------------------------------------------------------------------
// Kernel 0 (R7-verified): W = [Wq;Wk;Wv] -> bf16, frag-major + pre-swizzled:
//   Wp[kc*6144 + (((g*192 + col) ^ g) << 3) + kl] = W[col][kc*32 + g*8 + kl]
// ---------------------------------------------------------------------------
__global__ void wconv(const float* __restrict__ Wq, const float* __restrict__ Wk,
                      const float* __restrict__ Wv, short* __restrict__ Wp) {
    int i = blockIdx.x * 256 + threadIdx.x;
    if (i >= 192 * 384) return;
    int col = i / 384;
    int k   = i - col * 384;
    const float* src = col < 64 ? (Wq + col * 384)
                     : col < 128 ? (Wk + (col - 64) * 384)
                                 : (Wv + (col - 128) * 384);
    int kc = k >> 5, g = (k >> 3) & 3, kl = k & 7;
    Wp[kc * 6144 + (((g * 192 + col) ^ g) << 3) + kl] = (short)f2bf(src[k]);
}

// ---------------------------------------------------------------------------
// Kernel 1: QKV projection with T3/T4 counted-vmcnt pipeline (the one lever
// never yet applied; every prior round drained vmcnt(0) per step -> issue
// gaps -> 1.1-1.4 TB/s).  R7 geometry: 512 blocks x 256 thr, tile 128x192,
// BK=32, 12 steps, 4 waves (2Mx2N, wave 64x96).  ALL staging via
// global_load_lds (no dest VGPRs -> compiler emits no vmcnt; manual counts
// authoritative).  x TRIPLE-buffered, W double-buffered (L2-hot).
// Per step s: issue W(s+1), X(s+2) -> compute s -> s_waitcnt vmcnt(4)
// (X(s+2)'s 4 loads STAY IN FLIGHT across the barrier) -> RAW s_barrier
// (__syncthreads would re-insert the vmcnt(0) drain).  Tail: vmcnt(0) @ s=10.
// x layout: linear LDS + source-preswizzle (R7-verified); W: Wp pack (R7).
// LDS 72 KB -> 2 blocks/CU.  Epilogue overlays x buffers (48 KB).
// ---------------------------------------------------------------------------
__global__ __launch_bounds__(256, 2) void qkv_proj(
    const float* __restrict__ x, const short* __restrict__ Wp,
    short* __restrict__ Qw, short* __restrict__ Kw, short* __restrict__ Vw) {
    __shared__ unsigned char LDSRAW[73728];   // x: 3x16KB | W: 2x12KB

    const int tid = threadIdx.x;
    const int wv = tid >> 6, lane = tid & 63;
    const int g = lane >> 4, c = lane & 15;
    const int wm = (wv >> 1) * 64, wn = (wv & 1) * 96;
    const size_t m0 = (size_t)blockIdx.x * 128;

    // per-lane source-swizzle constants for x staging (R7-verified)
    const int xrow8 = lane >> 3;                       // 0..7
    const int xgcol = ((lane & 7) ^ xrow8) << 2;       // swizzled f32 chunk

#define XBUF(I) ((float*)(LDSRAW + ((I) % 3) * 16384))
#define WBUF(I) ((short*)(LDSRAW + 49152 + ((I) % 2) * 12288))
#define STAGE_X(KC)                                                          \
    {                                                                        \
        float* xb_ = XBUF(KC);                                               \
        _Pragma("unroll")                                                    \
        for (int i_ = 0; i_ < 4; ++i_) {                                     \
            int seg = wv * 4 + i_;                                           \
            const float* gp = x + (m0 + seg * 8 + xrow8) * 384 + (KC) * 32 + xgcol; \
            gload16(gp, xb_ + seg * 256);                                    \
        }                                                                    \
    }
#define STAGE_W(KC)                                                          \
    {                                                                        \
        short* wb_ = WBUF(KC);                                               \
        _Pragma("unroll")                                                    \
        for (int i_ = 0; i_ < 3; ++i_) {                                     \
            int seg = wv * 3 + i_;                                           \
            gload16(Wp + (KC) * 6144 + seg * 512 + lane * 8, wb_ + seg * 512); \
        }                                                                    \
    }

    f32x4 acc[4][6];
#pragma unroll
    for (int i = 0; i < 4; ++i)
#pragma unroll
        for (int j = 0; j < 6; ++j) acc[i][j] = (f32x4){0.f, 0.f, 0.f, 0.f};

    // prologue: FIFO = [X0, W0, X1]; wait to 4 -> X0,W0 done, X1 in flight
    STAGE_X(0)
    STAGE_W(0)
    STAGE_X(1)
    asm volatile("s_waitcnt vmcnt(4)" ::: "memory");
    __builtin_amdgcn_s_barrier();
    __builtin_amdgcn_sched_barrier(0);

#pragma unroll
    for (int s = 0; s < 12; ++s) {
        // issue-ahead (targets not read until s+1 / s+2; barrier of s-1 passed)
        if (s <= 10) STAGE_W(s + 1)
        if (s <= 9)  STAGE_X(s + 2)
        // compute step s
        const float* xb = XBUF(s);
        const short* wb = WBUF(s);
        bf16x8 af[4], bfr[6];
#pragma unroll
        for (int mi = 0; mi < 4; ++mi) {
            const int row = wm + 16 * mi + c;
            const int rx = row & 7;
            f32x4 lo = *(const f32x4*)&xb[row * 32 + (((2 * g) ^ rx) << 2)];
            f32x4 hi = *(const f32x4*)&xb[row * 32 + (((2 * g + 1) ^ rx) << 2)];
            bf16x8 t;
            t[0] = (short)f2bf(lo[0]); t[1] = (short)f2bf(lo[1]);
            t[2] = (short)f2bf(lo[2]); t[3] = (short)f2bf(lo[3]);
            t[4] = (short)f2bf(hi[0]); t[5] = (short)f2bf(hi[1]);
            t[6] = (short)f2bf(hi[2]); t[7] = (short)f2bf(hi[3]);
            af[mi] = t;
        }
#pragma unroll
        for (int nj = 0; nj < 6; ++nj)
            bfr[nj] = *(const bf16x8*)&wb[((g * 192 + wn + 16 * nj + c) ^ g) << 3];
#pragma unroll
        for (int mi = 0; mi < 4; ++mi)
#pragma unroll
            for (int nj = 0; nj < 6; ++nj)
                acc[mi][nj] = __builtin_amdgcn_mfma_f32_16x16x32_bf16(
                    af[mi], bfr[nj], acc[mi][nj], 0, 0, 0);
        // counted wait: s+1's X,W drained; X(s+2) (4 loads) stays in flight
        if (s <= 9)       asm volatile("s_waitcnt vmcnt(4)" ::: "memory");
        else if (s == 10) asm volatile("s_waitcnt vmcnt(0)" ::: "memory");
        __builtin_amdgcn_s_barrier();
        __builtin_amdgcn_sched_barrier(0);
    }

    // epilogue: acc -> LDS repack (overlays x buffers) -> coalesced stores.
    // C/D layout (verified): col = c, row = 4g + r within each 16x16 tile.
    __syncthreads();
    short* ep = (short*)LDSRAW;             // 128*192 shorts = 49152 B
#pragma unroll
    for (int mi = 0; mi < 4; ++mi)
#pragma unroll
        for (int nj = 0; nj < 6; ++nj) {
            const int row = wm + 16 * mi + 4 * g;
#pragma unroll
            for (int r = 0; r < 4; ++r)
                ep[(row + r) * 192 + wn + 16 * nj + c] = (short)f2bf(acc[mi][nj][r]);
        }
    __syncthreads();
#pragma unroll
    for (int p = 0; p < 4; ++p) {
        int u = tid + 256 * p;              // 0..1023: row = u>>3, c8 = u&7
        int row = u >> 3, c8 = u & 7;
        *(uint4*)(Qw + (m0 + row) * 64 + c8 * 8) = *(const uint4*)&ep[row * 192 + c8 * 8];
        *(uint4*)(Kw + (m0 + row) * 64 + c8 * 8) = *(const uint4*)&ep[row * 192 + 64 + c8 * 8];
        *(uint4*)(Vw + (m0 + row) * 64 + c8 * 8) = *(const uint4*)&ep[row * 192 + 128 + c8 * 8];
    }
#undef STAGE_X
#undef STAGE_W
#undef XBUF
#undef WBUF
}

// ---------------------------------------------------------------------------
// Kernel 2: causal attention (R2/R7-verified, verbatim). 256 blocks x 512 thr,
// LDS 79 KB -> 2 blocks/CU. K [256][72]; V transposed [64][264] XOR-swizzled;
// Q direct global->regs. Wave w: q-tiles 16w and 240-16w (9 kv-tiles each).
// ---------------------------------------------------------------------------
__global__ __launch_bounds__(512, 2) void attn_mfma(
    const short* __restrict__ Qw, const short* __restrict__ Kw,
    const short* __restrict__ Vw, float* __restrict__ out) {
    __shared__ short Ksh[256 * 72];
    __shared__ short Vt[64 * 264];
    __shared__ short Pb[8][640];
    const int tid = threadIdx.x;
    const int wv = tid >> 6, lane = tid & 63;
    const int g = lane >> 4, c = lane & 15;
    const int b = blockIdx.x;
    const short* Qg = Qw + b * 16384;
    const short* Kg = Kw + b * 16384;
    const short* Vg = Vw + b * 16384;

#pragma unroll
    for (int p = 0; p < 4; ++p) {
        int idx = tid + 512 * p;
        int r = idx >> 3, q8 = idx & 7;
        *(uint4*)&Ksh[r * 72 + q8 * 8] = *(const uint4*)(Kg + r * 64 + q8 * 8);
    }
#pragma unroll
    for (int p = 0; p < 4; ++p) {
        int idx = tid + 512 * p;
        int r = idx >> 3, q8 = idx & 7;
        uint4 v = *(const uint4*)(Vg + r * 64 + q8 * 8);
        unsigned vw[4] = {v.x, v.y, v.z, v.w};
        int swz = (q8 & 7) << 3;
#pragma unroll
        for (int w2 = 0; w2 < 4; ++w2) {
            int h0 = q8 * 8 + w2 * 2;
            Vt[((h0 + 0) * 264 + r) ^ swz] = (short)(vw[w2] & 0xffff);
            Vt[((h0 + 1) * 264 + r) ^ swz] = (short)(vw[w2] >> 16);
        }
    }
    __syncthreads();

    for (int half = 0; half < 2; ++half) {
        const int q0 = (half == 0) ? 16 * wv : 240 - 16 * wv;
        bf16x8 qf0 = *(const bf16x8*)(Qg + (q0 + c) * 64 + g * 8);
        bf16x8 qf1 = *(const bf16x8*)(Qg + (q0 + c) * 64 + 32 + g * 8);
        f32x4 o[4];
#pragma unroll
        for (int nj = 0; nj < 4; ++nj) o[nj] = (f32x4){0.f, 0.f, 0.f, 0.f};
        float m[4] = {-INFINITY, -INFINITY, -INFINITY, -INFINITY};
        float ls[4] = {0.f, 0.f, 0.f, 0.f};
        const int jmax = (q0 + 15) >> 5;

        for (int j = 0; j <= jmax; ++j) {
            f32x4 s0 = {0.f, 0.f, 0.f, 0.f}, s1 = {0.f, 0.f, 0.f, 0.f};
            {
                bf16x8 kf;
                kf = *(const bf16x8*)&Ksh[(32 * j + c) * 72 + g * 8];
                s0 = __builtin_amdgcn_mfma_f32_16x16x32_bf16(qf0, kf, s0, 0, 0, 0);
                kf = *(const bf16x8*)&Ksh[(32 * j + c) * 72 + 32 + g * 8];
                s0 = __builtin_amdgcn_mfma_f32_16x16x32_bf16(qf1, kf, s0, 0, 0, 0);
                kf = *(const bf16x8*)&Ksh[(32 * j + 16 + c) * 72 + g * 8];
                s1 = __builtin_amdgcn_mfma_f32_16x16x32_bf16(qf0, kf, s1, 0, 0, 0);
                kf = *(const bf16x8*)&Ksh[(32 * j + 16 + c) * 72 + 32 + g * 8];
                s1 = __builtin_amdgcn_mfma_f32_16x16x32_bf16(qf1, kf, s1, 0, 0, 0);
            }
            float t0[4], t1[4];
#pragma unroll
            for (int r = 0; r < 4; ++r) {
                t0[r] = s0[r] * 0.125f;
                t1[r] = s1[r] * 0.125f;
            }
            if (j == jmax) {   // wave-uniform: diagonal tile, causal mask
                int q = q0 + 4 * g;
#pragma unroll
                for (int r = 0; r < 4; ++r) {
                    if (32 * j + c > q + r) t0[r] = -INFINITY;
                    if (32 * j + 16 + c > q + r) t1[r] = -INFINITY;
                }
            }
            float corr[4], p0[4], p1[4];
#pragma unroll
            for (int r = 0; r < 4; ++r) {
                float v = fmaxf(t0[r], t1[r]);
#pragma unroll
                for (int off = 1; off < 16; off <<= 1) v = fmaxf(v, __shfl_xor(v, off, 16));
                float mn = fmaxf(m[r], v);
                corr[r] = __expf(m[r] - mn);   // first tile: exp(-inf)=0
                m[r] = mn;
                p0[r] = __expf(t0[r] - mn);
                p1[r] = __expf(t1[r] - mn);
                float rs = p0[r] + p1[r];
#pragma unroll
                for (int off = 1; off < 16; off <<= 1) rs += __shfl_xor(rs, off, 16);
                ls[r] = ls[r] * corr[r] + rs;
            }
#pragma unroll
            for (int nj = 0; nj < 4; ++nj) {
                f32x4 t = o[nj];
                t[0] *= corr[0]; t[1] *= corr[1]; t[2] *= corr[2]; t[3] *= corr[3];
                o[nj] = t;
            }
            short* pb = Pb[wv];
#pragma unroll
            for (int r = 0; r < 4; ++r) {
                pb[(4 * g + r) * 40 + c]      = (short)f2bf(p0[r]);
                pb[(4 * g + r) * 40 + 16 + c] = (short)f2bf(p1[r]);
            }
            bf16x8 pfa = *(const bf16x8*)&pb[c * 40 + g * 8];
#pragma unroll
            for (int nj = 0; nj < 4; ++nj) {
                int h = 16 * nj + c;
                int swz = ((2 * nj + (c >> 3)) & 7) << 3;
                bf16x8 vf = *(const bf16x8*)&Vt[(h * 264 + 32 * j + g * 8) ^ swz];
                o[nj] = __builtin_amdgcn_mfma_f32_16x16x32_bf16(pfa, vf, o[nj], 0, 0, 0);
            }
        }
        float inv[4];
#pragma unroll
        for (int r = 0; r < 4; ++r) inv[r] = 1.f / ls[r];
        float* ob = out + ((size_t)b * 256 + q0) * 64;
#pragma unroll
        for (int nj = 0; nj < 4; ++nj)
#pragma unroll
            for (int r = 0; r < 4; ++r)
                ob[(4 * g + r) * 64 + 16 * nj + c] = o[nj][r] * inv[r];
    }
}

// ---------------------------------------------------------------------------
extern "C" void kernel_launch(void* const* d_in, const int* in_sizes, int n_in,
                              void* d_out, int out_size, void* d_ws, size_t ws_size,
                              hipStream_t stream) {
    const float* x  = (const float*)d_in[0];
    const float* Wq = (const float*)d_in[1];
    const float* Wk = (const float*)d_in[2];
    const float* Wv = (const float*)d_in[3];
    float* out = (float*)d_out;

    // ws: Q | K | V (each 65536*64 bf16 = 8 MB) | Wp (73728 shorts)
    short* Qws = (short*)d_ws;
    short* Kws = Qws + (size_t)65536 * 64;
    short* Vws = Kws + (size_t)65536 * 64;
    short* Wp  = Vws + (size_t)65536 * 64;

    wconv<<<dim3(288), dim3(256), 0, stream>>>(Wq, Wk, Wv, Wp);
    qkv_proj<<<dim3(512), dim3(256), 0, stream>>>(x, Wp, Qws, Kws, Vws);
    attn_mfma<<<dim3(256), dim3(512), 0, stream>>>(Qws, Kws, Vws, out);
}

// Round 12
// 41.100 us; speedup vs baseline: 1.4118x; 1.1453x over previous
//
#include <hip/hip_runtime.h>

// B=256, T=256, D=384, HD=64
typedef __attribute__((ext_vector_type(8))) short bf16x8;
typedef __attribute__((ext_vector_type(4))) float f32x4;

__device__ inline unsigned short f2bf(float f) {
    unsigned u = __float_as_uint(f);
    return (unsigned short)((u + 0x7fffu + ((u >> 16) & 1u)) >> 16);
}
__device__ inline void gload16(const void* g, void* l) {
    __builtin_amdgcn_global_load_lds(
        (const __attribute__((address_space(1))) unsigned*)g,
        (__attribute__((address_space(3))) unsigned*)l, 16, 0, 0);
}

// ---------------------------------------------------------------------------
// Kernel 0 (R7/R9-verified): W = [Wq;Wk;Wv] -> bf16 frag-major pre-swizzled:
//   Wp[kc*6144 + (((g*192 + col) ^ g) << 3) + kl] = W[col][kc*32 + g*8 + kl]
// ---------------------------------------------------------------------------
__global__ void wconv(const float* __restrict__ Wq, const float* __restrict__ Wk,
                      const float* __restrict__ Wv, short* __restrict__ Wp) {
    int i = blockIdx.x * 256 + threadIdx.x;
    if (i >= 192 * 384) return;
    int col = i / 384;
    int k   = i - col * 384;
    const float* src = col < 64 ? (Wq + col * 384)
                     : col < 128 ? (Wk + (col - 64) * 384)
                                 : (Wv + (col - 128) * 384);
    int kc = k >> 5, g = (k >> 3) & 3, kl = k & 7;
    Wp[kc * 6144 + (((g * 192 + col) ^ g) << 3) + kl] = (short)f2bf(src[k]);
}

// ---------------------------------------------------------------------------
// Fused kernel v3 = R9 (42.7 us best) with phase-1 rescheduled T3/T4-style
// at 1 block/CU (the only occupancy fusion permits; register math forbids 2
// blocks/CU for a 256-row tile).  Per step: issue W(s+1) via global_load_lds,
// issue x(s+2) to a static triple register set, compute, convert+ds_write
// x(s+1), then PER-WAVE counted s_waitcnt (staging waves: vmcnt(2) -> W
// drained, x(s+2) STAYS IN FLIGHT across the RAW s_barrier; waves 12-15:
// no wait).  sched_barrier(0) fences pin the VMEM FIFO order so the counts
// are valid.  lgkmcnt(0) covers the ds_writes before each barrier.
// Everything else (LDS overlays, epilogue layouts, Q-through-Pb, phase 2)
// is R9-verbatim.
// ---------------------------------------------------------------------------
__global__ __launch_bounds__(1024) void fused_attn(
    const float* __restrict__ x, const short* __restrict__ Wp,
    float* __restrict__ out) {
    __shared__ short LDSH[45568];          // 91136 B
    short* const Ksh = LDSH;               // [256*72]
    short* const Vt  = LDSH + 18432;       // [64*264]
    short* const Pb  = LDSH + 35328;       // [16*640]
    short* const wst = LDSH;               // W dbuf overlay: 2*6144
    short* const xst = LDSH + 18432;       // x dbuf overlay: 2*10240

    const int tid = threadIdx.x;
    const int wv = tid >> 6, lane = tid & 63;
    const int g = lane >> 4, c = lane & 15;
    const int b = blockIdx.x;
    const int q0 = wv * 16;

    // x staging map: thread -> row xr0 & xr0+128, f32 chunk xc4
    const int xr0 = tid >> 3;              // 0..127
    const int xc4 = tid & 7;
    const float* gx0 = x + ((size_t)b * 256 + xr0) * 384 + xc4 * 4;
    const float* gx1 = gx0 + (size_t)128 * 384;

    f32x4 acc[12];
#pragma unroll
    for (int j = 0; j < 12; ++j) acc[j] = (f32x4){0.f, 0.f, 0.f, 0.f};

#define STAGE_W(S, BUF)                                                       \
    if (wv < 12) gload16(Wp + (S) * 6144 + wv * 512 + lane * 8,               \
                         wst + (BUF) * 6144 + wv * 512);
#define XWRITE(BUF, A, Bv)                                                    \
    {                                                                         \
        uint2 p0_, p1_;                                                       \
        p0_.x = (unsigned)f2bf((A).x) | ((unsigned)f2bf((A).y) << 16);        \
        p0_.y = (unsigned)f2bf((A).z) | ((unsigned)f2bf((A).w) << 16);        \
        p1_.x = (unsigned)f2bf((Bv).x) | ((unsigned)f2bf((Bv).y) << 16);      \
        p1_.y = (unsigned)f2bf((Bv).z) | ((unsigned)f2bf((Bv).w) << 16);      \
        *(uint2*)&xst[(BUF) * 10240 + xr0 * 40 + xc4 * 4] = p0_;              \
        *(uint2*)&xst[(BUF) * 10240 + (xr0 + 128) * 40 + xc4 * 4] = p1_;      \
    }
#define COMPUTE(S)                                                            \
    {                                                                         \
        const short* xb = xst + ((S) & 1) * 10240;                            \
        const short* wb = wst + ((S) & 1) * 6144;                             \
        bf16x8 af = *(const bf16x8*)&xb[(q0 + c) * 40 + g * 8];               \
        _Pragma("unroll")                                                     \
        for (int h_ = 0; h_ < 2; ++h_) {                                      \
            bf16x8 bfr[6];                                                    \
            _Pragma("unroll")                                                 \
            for (int j6 = 0; j6 < 6; ++j6) {                                  \
                int col = (h_ * 6 + j6) * 16 + c;                             \
                bfr[j6] = *(const bf16x8*)&wb[((g * 192 + col) ^ g) << 3];    \
            }                                                                 \
            _Pragma("unroll")                                                 \
            for (int j6 = 0; j6 < 6; ++j6)                                    \
                acc[h_ * 6 + j6] = __builtin_amdgcn_mfma_f32_16x16x32_bf16(   \
                    af, bfr[j6], acc[h_ * 6 + j6], 0, 0, 0);                  \
    }                                                                         \
    }
// STEP(S): issue W(S+1); issue x(S+2) into (LX0,LX1); compute S;
//          convert+write x(S+1) from (WX0,WX1); counted waits; raw barrier.
#define STEP(S, LX0, LX1, WX0, WX1)                                          \
    {                                                                        \
        STAGE_W((S) + 1, ((S) + 1) & 1)                                      \
        __builtin_amdgcn_sched_barrier(0);                                   \
        if ((S) <= 9) {                                                      \
            LX0 = *(const float4*)(gx0 + ((S) + 2) * 32);                    \
            LX1 = *(const float4*)(gx1 + ((S) + 2) * 32);                    \
        }                                                                    \
        __builtin_amdgcn_sched_barrier(0);                                   \
        COMPUTE(S)                                                           \
        XWRITE(((S) + 1) & 1, WX0, WX1)                                      \
        if (wv < 12) {                                                       \
            if ((S) <= 9) asm volatile("s_waitcnt vmcnt(2)" ::: "memory");   \
            else          asm volatile("s_waitcnt vmcnt(0)" ::: "memory");   \
        }                                                                    \
        asm volatile("s_waitcnt lgkmcnt(0)" ::: "memory");                   \
        __builtin_amdgcn_s_barrier();                                        \
        __builtin_amdgcn_sched_barrier(0);                                   \
    }

    float4 xA0, xA1, xB0, xB1, xC0, xC1;

    // ---- prologue: x0 -> A, W0, x1 -> B (FIFO pinned); write x0; keep x1 ----
    xA0 = *(const float4*)(gx0);
    xA1 = *(const float4*)(gx1);
    __builtin_amdgcn_sched_barrier(0);
    STAGE_W(0, 0)
    __builtin_amdgcn_sched_barrier(0);
    xB0 = *(const float4*)(gx0 + 32);
    xB1 = *(const float4*)(gx1 + 32);
    __builtin_amdgcn_sched_barrier(0);
    XWRITE(0, xA0, xA1)                    // compiler auto-waits x0 only
    if (wv < 12) asm volatile("s_waitcnt vmcnt(2)" ::: "memory");  // W0 done
    asm volatile("s_waitcnt lgkmcnt(0)" ::: "memory");
    __builtin_amdgcn_s_barrier();
    __builtin_amdgcn_sched_barrier(0);

    // ---- 12 steps; x(k) lives in set k%3 (A=0,B=1,C=2), all static ----
    STEP(0, xC0, xC1, xB0, xB1)
    STEP(1, xA0, xA1, xC0, xC1)
    STEP(2, xB0, xB1, xA0, xA1)
    STEP(3, xC0, xC1, xB0, xB1)
    STEP(4, xA0, xA1, xC0, xC1)
    STEP(5, xB0, xB1, xA0, xA1)
    STEP(6, xC0, xC1, xB0, xB1)
    STEP(7, xA0, xA1, xC0, xC1)
    STEP(8, xB0, xB1, xA0, xA1)
    STEP(9, xC0, xC1, xB0, xB1)
    STEP(10, xA0, xA1, xC0, xC1)           // no load (S>9); writes x11=C
    COMPUTE(11)
    __syncthreads();

    // ---- epilogue (R9-verbatim): acc -> K/V LDS; Q -> regs via per-wave Pb.
    // C/D layout (verified): within 16x16 tile, col = c, row = 4g + r.
    short* const pbw = Pb + wv * 640;
    bf16x8 qf0, qf1;
    {
#pragma unroll
        for (int r = 0; r < 4; ++r) {
            pbw[(4 * g + r) * 40 + c]      = (short)f2bf(acc[0][r]);
            pbw[(4 * g + r) * 40 + 16 + c] = (short)f2bf(acc[1][r]);
        }
        qf0 = *(const bf16x8*)&pbw[c * 40 + g * 8];
#pragma unroll
        for (int r = 0; r < 4; ++r) {
            pbw[(4 * g + r) * 40 + c]      = (short)f2bf(acc[2][r]);
            pbw[(4 * g + r) * 40 + 16 + c] = (short)f2bf(acc[3][r]);
        }
        qf1 = *(const bf16x8*)&pbw[c * 40 + g * 8];
    }
#pragma unroll
    for (int nj = 4; nj < 8; ++nj) {
        const int row = q0 + 4 * g;
#pragma unroll
        for (int r = 0; r < 4; ++r)
            Ksh[(row + r) * 72 + (nj - 4) * 16 + c] = (short)f2bf(acc[nj][r]);
    }
#pragma unroll
    for (int nj = 8; nj < 12; ++nj) {
        const int h = (nj - 8) * 16 + c;
        const int swz = ((h >> 3) & 7) << 3;
        const int row = q0 + 4 * g;
#pragma unroll
        for (int r = 0; r < 4; ++r)
            Vt[(h * 264 + row + r) ^ swz] = (short)f2bf(acc[nj][r]);
    }
    __syncthreads();

    // ---------------- Phase 2: causal attention (R9-verbatim) ----------------
    {
        f32x4 o[4];
#pragma unroll
        for (int nj = 0; nj < 4; ++nj) o[nj] = (f32x4){0.f, 0.f, 0.f, 0.f};
        float m[4] = {-INFINITY, -INFINITY, -INFINITY, -INFINITY};
        float ls[4] = {0.f, 0.f, 0.f, 0.f};
        const int jmax = (q0 + 15) >> 5;

        for (int j = 0; j <= jmax; ++j) {
            f32x4 s0 = {0.f, 0.f, 0.f, 0.f}, s1 = {0.f, 0.f, 0.f, 0.f};
            {
                bf16x8 kf;
                kf = *(const bf16x8*)&Ksh[(32 * j + c) * 72 + g * 8];
                s0 = __builtin_amdgcn_mfma_f32_16x16x32_bf16(qf0, kf, s0, 0, 0, 0);
                kf = *(const bf16x8*)&Ksh[(32 * j + c) * 72 + 32 + g * 8];
                s0 = __builtin_amdgcn_mfma_f32_16x16x32_bf16(qf1, kf, s0, 0, 0, 0);
                kf = *(const bf16x8*)&Ksh[(32 * j + 16 + c) * 72 + g * 8];
                s1 = __builtin_amdgcn_mfma_f32_16x16x32_bf16(qf0, kf, s1, 0, 0, 0);
                kf = *(const bf16x8*)&Ksh[(32 * j + 16 + c) * 72 + 32 + g * 8];
                s1 = __builtin_amdgcn_mfma_f32_16x16x32_bf16(qf1, kf, s1, 0, 0, 0);
            }
            float t0[4], t1[4];
#pragma unroll
            for (int r = 0; r < 4; ++r) {
                t0[r] = s0[r] * 0.125f;
                t1[r] = s1[r] * 0.125f;
            }
            if (j == jmax) {   // wave-uniform: diagonal tile, causal mask
                int q = q0 + 4 * g;
#pragma unroll
                for (int r = 0; r < 4; ++r) {
                    if (32 * j + c > q + r) t0[r] = -INFINITY;
                    if (32 * j + 16 + c > q + r) t1[r] = -INFINITY;
                }
            }
            float corr[4], p0[4], p1[4];
#pragma unroll
            for (int r = 0; r < 4; ++r) {
                float v = fmaxf(t0[r], t1[r]);
#pragma unroll
                for (int off = 1; off < 16; off <<= 1) v = fmaxf(v, __shfl_xor(v, off, 16));
                float mn = fmaxf(m[r], v);
                corr[r] = __expf(m[r] - mn);   // first tile: exp(-inf)=0
                m[r] = mn;
                p0[r] = __expf(t0[r] - mn);
                p1[r] = __expf(t1[r] - mn);
                float rs = p0[r] + p1[r];
#pragma unroll
                for (int off = 1; off < 16; off <<= 1) rs += __shfl_xor(rs, off, 16);
                ls[r] = ls[r] * corr[r] + rs;
            }
#pragma unroll
            for (int nj = 0; nj < 4; ++nj) {
                f32x4 t = o[nj];
                t[0] *= corr[0]; t[1] *= corr[1]; t[2] *= corr[2]; t[3] *= corr[3];
                o[nj] = t;
            }
            // P -> Pb (C/D rows) -> A-frag read (same-wave RAW, in-order LDS)
#pragma unroll
            for (int r = 0; r < 4; ++r) {
                pbw[(4 * g + r) * 40 + c]      = (short)f2bf(p0[r]);
                pbw[(4 * g + r) * 40 + 16 + c] = (short)f2bf(p1[r]);
            }
            bf16x8 pfa = *(const bf16x8*)&pbw[c * 40 + g * 8];
#pragma unroll
            for (int nj = 0; nj < 4; ++nj) {
                int h = 16 * nj + c;
                int swz = ((2 * nj + (c >> 3)) & 7) << 3;
                bf16x8 vf = *(const bf16x8*)&Vt[(h * 264 + 32 * j + g * 8) ^ swz];
                o[nj] = __builtin_amdgcn_mfma_f32_16x16x32_bf16(pfa, vf, o[nj], 0, 0, 0);
            }
        }
        float inv[4];
#pragma unroll
        for (int r = 0; r < 4; ++r) inv[r] = 1.f / ls[r];
        float* ob = out + ((size_t)b * 256 + q0) * 64;
#pragma unroll
        for (int nj = 0; nj < 4; ++nj)
#pragma unroll
            for (int r = 0; r < 4; ++r)
                ob[(4 * g + r) * 64 + 16 * nj + c] = o[nj][r] * inv[r];
    }
#undef STAGE_W
#undef XWRITE
#undef COMPUTE
#undef STEP
}

// ---------------------------------------------------------------------------
extern "C" void kernel_launch(void* const* d_in, const int* in_sizes, int n_in,
                              void* d_out, int out_size, void* d_ws, size_t ws_size,
                              hipStream_t stream) {
    const float* x  = (const float*)d_in[0];
    const float* Wq = (const float*)d_in[1];
    const float* Wk = (const float*)d_in[2];
    const float* Wv = (const float*)d_in[3];
    float* out = (float*)d_out;

    short* Wp = (short*)d_ws;   // 73728 shorts (144 KB)

    wconv<<<dim3(288), dim3(256), 0, stream>>>(Wq, Wk, Wv, Wp);
    fused_attn<<<dim3(256), dim3(1024), 0, stream>>>(x, Wp, out);
}